// Round 6
// baseline (3739.697 us; speedup 1.0000x reference)
//
#include <hip/hip_runtime.h>
#include <hip/hip_bf16.h>
#include <cstdint>
#include <cstddef>

// Problem constants
#define KBLK 6
#define SL 257
#define BA 64
#define DM 1024
#define NHEAD 16
#define DRED 256
#define HDM 16
#define MR (SL * BA)     // 16448 real rows
#define MP 16512         // 129 * 128 padded rows
#define LNEPS 1e-5f

typedef __hip_bfloat16 bf16;
typedef __attribute__((ext_vector_type(8))) short short8;
typedef __attribute__((ext_vector_type(4))) short short4_t;
typedef __attribute__((ext_vector_type(4))) float f32x4;

// ---------------- async global -> LDS (16B per lane) ----------------
__device__ __forceinline__ void gld_lds16(const void* g, void* l) {
  __builtin_amdgcn_global_load_lds(
      (const __attribute__((address_space(1))) unsigned int*)g,
      (__attribute__((address_space(3))) unsigned int*)l, 16, 0, 0);
}

__device__ __forceinline__ float bf2f(short s) {
  bf16 t = *reinterpret_cast<bf16*>(&s);
  return __bfloat162float(t);
}
__device__ __forceinline__ short f2bf(float f) {
  bf16 t = __float2bfloat16(f);
  return *reinterpret_cast<short*>(&t);
}

// ---------------- weight casts ----------------
__global__ __launch_bounds__(256) void cast_bf16_kernel(const float* __restrict__ src,
                                                        bf16* __restrict__ dst, int n) {
  int i = blockIdx.x * 256 + threadIdx.x;
  int stride = gridDim.x * 256;
  for (; i < n; i += stride) dst[i] = __float2bfloat16(src[i]);
}

__global__ __launch_bounds__(256) void cast_projT_kernel(const float* __restrict__ proj,
                                                         bf16* __restrict__ dst) {
  // proj: (DM, 768) -> dst: (768, DM)
  int i = blockIdx.x * 256 + threadIdx.x;
  if (i < 768 * DM) {
    int n = i >> 10, k = i & (DM - 1);
    dst[i] = __float2bfloat16(proj[k * 768 + n]);
  }
}

// ---------------- LayerNorm ----------------
// MODE 0: x = bf16(hook); LN(hook) -> hout
// MODE 2: LN(x) -> hout
// MODE 3: LN(x) -> hout at transposed row (b*SL+s)  [ln_post]
template <int MODE>
__global__ __launch_bounds__(256) void ln_kernel(
    const float* __restrict__ hook,
    bf16* __restrict__ x, bf16* __restrict__ hout,
    const float* __restrict__ w, const float* __restrict__ bb) {
  const int row = blockIdx.x;
  const int tid = threadIdx.x;
  const size_t base = (size_t)row * DM + tid * 4;
  float vals[4];
  if (MODE == 0) {
    float4 v = *(const float4*)(hook + base);
    vals[0] = v.x; vals[1] = v.y; vals[2] = v.z; vals[3] = v.w;
    short4_t pk;
#pragma unroll
    for (int j = 0; j < 4; ++j) pk[j] = f2bf(vals[j]);
    *(short4_t*)&x[base] = pk;
  } else {
    short4_t xv = *(const short4_t*)&x[base];
#pragma unroll
    for (int j = 0; j < 4; ++j) vals[j] = bf2f(xv[j]);
  }
  float s1 = vals[0] + vals[1] + vals[2] + vals[3];
  float s2 = vals[0] * vals[0] + vals[1] * vals[1] + vals[2] * vals[2] + vals[3] * vals[3];
#pragma unroll
  for (int o = 32; o >= 1; o >>= 1) {
    s1 += __shfl_down(s1, o);
    s2 += __shfl_down(s2, o);
  }
  __shared__ float red[8];
  if ((tid & 63) == 0) {
    red[tid >> 6] = s1;
    red[4 + (tid >> 6)] = s2;
  }
  __syncthreads();
  s1 = red[0] + red[1] + red[2] + red[3];
  s2 = red[4] + red[5] + red[6] + red[7];
  const float mu = s1 * (1.f / DM);
  const float rs = rsqrtf(s2 * (1.f / DM) - mu * mu + LNEPS);
  size_t orow = row;
  if (MODE == 3) {
    int s = row >> 6, b2 = row & 63;
    orow = (size_t)b2 * SL + s;
  }
  const int c = tid * 4;
  short4_t pk;
#pragma unroll
  for (int j = 0; j < 4; ++j)
    pk[j] = f2bf((vals[j] - mu) * rs * w[c + j] + bb[c + j]);
  *(short4_t*)((char*)hout + (orow * DM + c) * 2) = pk;
}

// ---------------- MFMA attention (unchanged, validated) ----------------
__global__ __launch_bounds__(256) void attn_mfma_kernel(const bf16* __restrict__ qkv,
                                                        bf16* __restrict__ obuf) {
  __shared__ __align__(16) short ql[272][24];
  __shared__ __align__(16) short kl[272][24];
  __shared__ __align__(16) short vt[16][296];
  __shared__ __align__(16) short pl[4][16][40];
  const int bh = blockIdx.x;
  const int b = bh >> 4, h = bh & 15;
  const int tid = threadIdx.x;
  const int wave = tid >> 6, lane = tid & 63;
  const int g = lane >> 4, qi = lane & 15;

  const short8 zero8 = {0, 0, 0, 0, 0, 0, 0, 0};
  const f32x4 fzero = {0.f, 0.f, 0.f, 0.f};

  for (int task = tid; task < 1632; task += 256) {
    int a, rem;
    if (task < 544) { a = 0; rem = task; }
    else if (task < 1088) { a = 1; rem = task - 544; }
    else { a = 2; rem = task - 1088; }
    int row = rem >> 1, half = rem & 1;
    short8 v = zero8;
    if (row < SL)
      v = *(const short8*)((const short*)qkv + (size_t)(row * BA + b) * 768 + a * 256 + h * 16 + half * 8);
    if (a == 0) *(short8*)&ql[row][half * 8] = v;
    else if (a == 1) *(short8*)&kl[row][half * 8] = v;
    else {
#pragma unroll
      for (int j = 0; j < 8; ++j) vt[half * 8 + j][row] = v[j];
    }
  }
  for (int i = tid; i < 16 * 24; i += 256) vt[i / 24][272 + (i % 24)] = 0;
  __syncthreads();

  for (int t = wave; t < 17; t += 4) {
    short8 bq = zero8;
    if (g < 2) bq = *(const short8*)&ql[t * 16 + qi][g * 8];

    f32x4 st[18];
#pragma unroll
    for (int t2 = 0; t2 < 17; ++t2) {
      short8 ak = zero8;
      if (g < 2) ak = *(const short8*)&kl[t2 * 16 + qi][g * 8];
      st[t2] = __builtin_amdgcn_mfma_f32_16x16x32_bf16(ak, bq, fzero, 0, 0, 0);
    }
    float mx = -1e30f;
#pragma unroll
    for (int t2 = 0; t2 < 17; ++t2) {
#pragma unroll
      for (int r = 0; r < 4; ++r) {
        int s = t2 * 16 + g * 4 + r;
        float v = (s <= 256) ? st[t2][r] * 0.25f : -1e30f;
        st[t2][r] = v;
        mx = fmaxf(mx, v);
      }
    }
    mx = fmaxf(mx, __shfl_xor(mx, 16));
    mx = fmaxf(mx, __shfl_xor(mx, 32));
    float ls = 0.f;
#pragma unroll
    for (int t2 = 0; t2 < 17; ++t2) {
#pragma unroll
      for (int r = 0; r < 4; ++r) {
        float p = __expf(st[t2][r] - mx);
        st[t2][r] = p;
        ls += p;
      }
    }
    ls += __shfl_xor(ls, 16);
    ls += __shfl_xor(ls, 32);
    const float inv = 1.f / ls;
#pragma unroll
    for (int t2 = 0; t2 < 17; ++t2)
#pragma unroll
      for (int r = 0; r < 4; ++r) st[t2][r] *= inv;
    st[17] = fzero;

    f32x4 acc = fzero;
#pragma unroll
    for (int tt = 0; tt < 9; ++tt) {
#pragma unroll
      for (int hh = 0; hh < 2; ++hh) {
        int t2 = tt * 2 + hh;
        short4_t pk;
#pragma unroll
        for (int r = 0; r < 4; ++r) pk[r] = f2bf(st[t2][r]);
        *(short4_t*)&pl[wave][qi][hh * 16 + g * 4] = pk;
      }
      short8 pa = *(const short8*)&pl[wave][qi][g * 8];
      short8 bv = *(const short8*)&vt[qi][tt * 32 + g * 8];
      acc = __builtin_amdgcn_mfma_f32_16x16x32_bf16(pa, bv, acc, 0, 0, 0);
    }
#pragma unroll
    for (int r = 0; r < 4; ++r) {
      int qr = t * 16 + g * 4 + r;
      if (qr < SL)
        obuf[(size_t)(qr * BA + b) * DRED + h * 16 + qi] = __float2bfloat16(acc[r]);
    }
  }
}

// ---------------- 128x128 GEMM (out_proj, K=256): x += A*B^T + bias (in-place RMW)
__global__ __launch_bounds__(256, 3) void gemm_op_kernel(
    const bf16* __restrict__ A, int lda,
    const bf16* __restrict__ Bw, int ldb,
    const float* __restrict__ bias,
    bf16* __restrict__ C, int ldc,
    int Kdim, int Mreal) {
  __shared__ char lds[32768];
  const int tid = threadIdx.x;
  const int wave = tid >> 6, lane = tid & 63;
  const int lrow = lane & 15, lk = lane >> 4;
  const int wr = wave >> 1, wc = wave & 1;

  const int gx = gridDim.x, gy = gridDim.y;
  const int nwg = gx * gy;
  const int orig = blockIdx.y * gx + blockIdx.x;
  const int q = nwg >> 3, r = nwg & 7;
  const int xcd = orig & 7, idx = orig >> 3;
  const int wgid = (xcd < r ? xcd * (q + 1) : r * (q + 1) + (xcd - r) * q) + idx;
  const int m0 = (wgid / gy) * 128;
  const int n0 = (wgid % gy) * 128;

  f32x4 acc[4][4];
  const f32x4 zero = {0.f, 0.f, 0.f, 0.f};
#pragma unroll
  for (int i = 0; i < 4; ++i)
#pragma unroll
    for (int j = 0; j < 4; ++j) acc[i][j] = zero;

  const int nk = Kdim >> 6;

  for (int kt = 0; kt < nk; ++kt) {
    const int k0 = kt << 6;
#pragma unroll
    for (int j = 0; j < 4; ++j) {
      int c = wave * 256 + j * 64 + lane;
      int row = c >> 3, segp = c & 7;
      int seg = segp ^ (row & 7);
      const bf16* ga = A + (size_t)(m0 + row) * lda + k0 + seg * 8;
      gld_lds16(ga, &lds[(wave * 256 + j * 64) * 16]);
      const bf16* gb = Bw + (size_t)(n0 + row) * ldb + k0 + seg * 8;
      gld_lds16(gb, &lds[16384 + (wave * 256 + j * 64) * 16]);
    }
    __syncthreads();
    const char* aL = &lds[0];
    const char* bL = aL + 16384;
#pragma unroll
    for (int kh = 0; kh < 2; ++kh) {
      short8 af[4], bfr[4];
#pragma unroll
      for (int i = 0; i < 4; ++i) {
        int rr = wr * 64 + i * 16 + lrow;
        int seg = kh * 4 + lk;
        af[i] = *(const short8*)(aL + rr * 128 + ((seg ^ (rr & 7)) << 4));
      }
#pragma unroll
      for (int j = 0; j < 4; ++j) {
        int rr = wc * 64 + j * 16 + lrow;
        int seg = kh * 4 + lk;
        bfr[j] = *(const short8*)(bL + rr * 128 + ((seg ^ (rr & 7)) << 4));
      }
#pragma unroll
      for (int i = 0; i < 4; ++i)
#pragma unroll
        for (int j = 0; j < 4; ++j)
          acc[i][j] = __builtin_amdgcn_mfma_f32_16x16x32_bf16(af[i], bfr[j], acc[i][j], 0, 0, 0);
    }
    __syncthreads();
  }

#pragma unroll
  for (int i = 0; i < 4; ++i) {
#pragma unroll
    for (int j = 0; j < 4; ++j) {
      int col = n0 + wc * 64 + j * 16 + lrow;
      float bv = bias[col];
#pragma unroll
      for (int rr = 0; rr < 4; ++rr) {
        int row = m0 + wr * 64 + i * 16 + lk * 4 + rr;
        if (row < Mreal) {
          size_t off = (size_t)row * ldc + col;
          bf16* p = C + off;
          *p = __float2bfloat16(__bfloat162float(*p) + acc[i][j][rr] + bv);
        }
      }
    }
  }
}

// ---------------- 128x256 GEMM (K=1024 shapes), m97-style 2-barrier loop ----------------
// Wider N-tile halves A/B panel re-fetch traffic (L2/L3-bound regime).
// 256 thr, 4 waves (2Mx2N), per-wave 64x128, acc[4][8]. LDS 48KB single buffer, 3 wg/CU.
// EPI 0: fp32 write (+0 bias ok)    EPI 1: bf16 in-place RMW  C += acc + bias
// EPI 2: bf16 quickgelu(acc+bias)   EPI 3: bf16 acc+bias
// EPI 4: bf16 in-place  x = wm*hook + (1-wm)*(x + acc + bias)
template <int EPI>
__global__ __launch_bounds__(256, 3) void gemm_w_kernel(
    const bf16* __restrict__ A, int lda,
    const bf16* __restrict__ Bw, int ldb,
    const float* __restrict__ bias,
    void* __restrict__ C, int ldc,
    int Kdim, int Mreal,
    const float* __restrict__ hook, const float* __restrict__ alphap, int kidx) {
  __shared__ char lds[49152];  // A 16KB | B 32KB
  const int tid = threadIdx.x;
  const int wave = tid >> 6, lane = tid & 63;
  const int lrow = lane & 15, lk = lane >> 4;
  const int wr = wave >> 1, wc = wave & 1;

  const int gx = gridDim.x, gy = gridDim.y;
  const int nwg = gx * gy;
  const int orig = blockIdx.y * gx + blockIdx.x;
  const int q = nwg >> 3, r = nwg & 7;
  const int xcd = orig & 7, idx = orig >> 3;
  const int wgid = (xcd < r ? xcd * (q + 1) : r * (q + 1) + (xcd - r) * q) + idx;
  const int m0 = (wgid / gy) * 128;
  const int n0 = (wgid % gy) * 256;

  f32x4 acc[4][8];
  const f32x4 zero = {0.f, 0.f, 0.f, 0.f};
#pragma unroll
  for (int i = 0; i < 4; ++i)
#pragma unroll
    for (int j = 0; j < 8; ++j) acc[i][j] = zero;

  const int nk = Kdim >> 6;

  for (int kt = 0; kt < nk; ++kt) {
    const int k0 = kt << 6;
    // A: 1024 16B segs (128 rows x 8)
#pragma unroll
    for (int j = 0; j < 4; ++j) {
      int c = wave * 256 + j * 64 + lane;
      int row = c >> 3;
      int seg = (c & 7) ^ (row & 7);
      gld_lds16(A + (size_t)(m0 + row) * lda + k0 + seg * 8, &lds[c * 16]);
    }
    // B: 2048 16B segs (256 rows x 8)
#pragma unroll
    for (int j = 0; j < 8; ++j) {
      int c = wave * 512 + j * 64 + lane;
      int row = c >> 3;
      int seg = (c & 7) ^ (row & 7);
      gld_lds16(Bw + (size_t)(n0 + row) * ldb + k0 + seg * 8, &lds[16384 + c * 16]);
    }
    __syncthreads();
#pragma unroll
    for (int kh = 0; kh < 2; ++kh) {
      short8 af[4], bfr[8];
#pragma unroll
      for (int i = 0; i < 4; ++i) {
        int rr = wr * 64 + i * 16 + lrow;
        int slot = (kh * 4 + lk) ^ (rr & 7);
        af[i] = *(const short8*)&lds[rr * 128 + slot * 16];
      }
#pragma unroll
      for (int j = 0; j < 8; ++j) {
        int rr = wc * 128 + j * 16 + lrow;
        int slot = (kh * 4 + lk) ^ (rr & 7);
        bfr[j] = *(const short8*)&lds[16384 + rr * 128 + slot * 16];
      }
#pragma unroll
      for (int i = 0; i < 4; ++i)
#pragma unroll
        for (int j = 0; j < 8; ++j)
          acc[i][j] = __builtin_amdgcn_mfma_f32_16x16x32_bf16(af[i], bfr[j], acc[i][j], 0, 0, 0);
    }
    __syncthreads();
  }

  float wmg = 0.f, omg = 0.f;
  if (EPI == 4) {
    wmg = 1.f / (1.f + __expf(-alphap[kidx] * 10.f));
    omg = 1.f - wmg;
  }
#pragma unroll
  for (int i = 0; i < 4; ++i) {
#pragma unroll
    for (int j = 0; j < 8; ++j) {
      int col = n0 + wc * 128 + j * 16 + lrow;
      float bv = bias ? bias[col] : 0.f;
#pragma unroll
      for (int rr = 0; rr < 4; ++rr) {
        int row = m0 + wr * 64 + i * 16 + lk * 4 + rr;
        if (row < Mreal) {
          float v = acc[i][j][rr] + bv;
          size_t off = (size_t)row * ldc + col;
          if (EPI == 0) {
            ((float*)C)[off] = v;
          } else if (EPI == 1) {
            bf16* p = (bf16*)C + off;
            *p = __float2bfloat16(__bfloat162float(*p) + v);
          } else if (EPI == 2) {
            float g2 = v / (1.f + __expf(-1.702f * v));
            ((bf16*)C)[off] = __float2bfloat16(g2);
          } else if (EPI == 3) {
            ((bf16*)C)[off] = __float2bfloat16(v);
          } else {  // EPI 4: gated residual, in-place
            bf16* p = (bf16*)C + off;
            float t = __bfloat162float(*p) + v;
            *p = __float2bfloat16(wmg * hook[off] + omg * t);
          }
        }
      }
    }
  }
}

// ---------------- driver ----------------
extern "C" void kernel_launch(void* const* d_in, const int* in_sizes, int n_in,
                              void* d_out, int out_size, void* d_ws, size_t ws_size,
                              hipStream_t stream) {
  const float* hook = (const float*)d_in[0];
  const float* alpha = (const float*)d_in[1];
  const float* ipw = (const float*)d_in[2];
  const float* ipb = (const float*)d_in[3];
  const float* opw = (const float*)d_in[4];
  const float* opb = (const float*)d_in[5];
  const float* l1w = (const float*)d_in[6];
  const float* l1b = (const float*)d_in[7];
  const float* l2w = (const float*)d_in[8];
  const float* l2b = (const float*)d_in[9];
  const float* fcw = (const float*)d_in[10];
  const float* fcb = (const float*)d_in[11];
  const float* cpw = (const float*)d_in[12];
  const float* cpb = (const float*)d_in[13];
  const float* lpw = (const float*)d_in[14];
  const float* lpb = (const float*)d_in[15];
  const float* proj = (const float*)d_in[16];

  char* ws = (char*)d_ws;
  size_t off = 0;
  bf16* x = (bf16*)(ws + off); off += (size_t)MP * DM * 2;
  bf16* hbuf = (bf16*)(ws + off); off += (size_t)MP * DM * 2;
  bf16* qkv = (bf16*)(ws + off);
  bf16* mbuf = (bf16*)qkv;  // reuse qkv region for MLP intermediate
  off += (size_t)MP * 1024 * 2;
  bf16* obuf = (bf16*)(ws + off); off += (size_t)MP * DRED * 2;
  bf16* wq = (bf16*)(ws + off); off += (size_t)KBLK * 768 * DM * 2;
  bf16* wo = (bf16*)(ws + off); off += (size_t)KBLK * DM * DRED * 2;
  bf16* wfc = (bf16*)(ws + off); off += (size_t)KBLK * DM * DM * 2;
  bf16* wcp = (bf16*)(ws + off); off += (size_t)KBLK * DM * DM * 2;
  bf16* wpj = (bf16*)(ws + off); off += (size_t)768 * DM * 2;

  // weight casts (deterministic, every call)
  cast_bf16_kernel<<<4096, 256, 0, stream>>>(ipw, wq, KBLK * 768 * DM);
  cast_bf16_kernel<<<2048, 256, 0, stream>>>(opw, wo, KBLK * DM * DRED);
  cast_bf16_kernel<<<4096, 256, 0, stream>>>(fcw, wfc, KBLK * DM * DM);
  cast_bf16_kernel<<<4096, 256, 0, stream>>>(cpw, wcp, KBLK * DM * DM);
  cast_projT_kernel<<<(768 * DM) / 256, 256, 0, stream>>>(proj, wpj);

  const dim3 gop(MP / 128, DM / 128);   // out_proj 128x128 grid
  const dim3 gq(MP / 128, 768 / 256);   // 128x256 grid, N=768
  const dim3 gm(MP / 128, DM / 256);    // 128x256 grid, N=1024

  for (int i = 0; i < KBLK; ++i) {
    if (i == 0)
      ln_kernel<0><<<MR, 256, 0, stream>>>(hook, x, hbuf, l1w, l1b);
    else
      ln_kernel<2><<<MR, 256, 0, stream>>>(nullptr, x, hbuf, l1w + i * DM, l1b + i * DM);
    // qkv = LN1(x) @ ipw^T + ipb (bf16)
    gemm_w_kernel<3><<<gq, 256, 0, stream>>>(hbuf, DM, wq + (size_t)i * 768 * DM, DM,
                                             ipb + i * 768, qkv, 768, DM, MR,
                                             nullptr, nullptr, 0);
    attn_mfma_kernel<<<BA * NHEAD, 256, 0, stream>>>(qkv, obuf);
    // x += attn_out @ opw^T + opb   (in-place RMW, disjoint tiles)
    gemm_op_kernel<<<gop, 256, 0, stream>>>(obuf, DRED, wo + (size_t)i * DM * DRED, DRED,
                                            opb + i * DM, x, DM, DRED, MR);
    ln_kernel<2><<<MR, 256, 0, stream>>>(nullptr, x, hbuf, l2w + i * DM, l2b + i * DM);
    // mbuf = quickgelu(LN2(x) @ fcw^T + fcb)
    gemm_w_kernel<2><<<gm, 256, 0, stream>>>(hbuf, DM, wfc + (size_t)i * DM * DM, DM,
                                             fcb + i * DM, mbuf, DM, DM, MR,
                                             nullptr, nullptr, 0);
    // x = [gate with next block's hook] (x + mbuf @ cpw^T + cpb)  (in-place RMW)
    if (i + 1 < KBLK)
      gemm_w_kernel<4><<<gm, 256, 0, stream>>>(mbuf, DM, wcp + (size_t)i * DM * DM, DM,
                                               cpb + i * DM, x, DM, DM, MR,
                                               hook + (size_t)(i + 1) * MR * DM, alpha, i + 1);
    else
      gemm_w_kernel<1><<<gm, 256, 0, stream>>>(mbuf, DM, wcp + (size_t)i * DM * DM, DM,
                                               cpb + i * DM, x, DM, DM, MR,
                                               nullptr, nullptr, 0);
  }
  // final: LN_post (transposed to (B,S,D)) then @ proj -> d_out (fp32)
  ln_kernel<3><<<MR, 256, 0, stream>>>(nullptr, x, hbuf, lpw, lpb);
  gemm_w_kernel<0><<<gq, 256, 0, stream>>>(hbuf, DM, wpj, DM, nullptr,
                                           (float*)d_out, 768, DM, MR,
                                           nullptr, nullptr, 0);
}

// Round 7
// 1796.603 us; speedup vs baseline: 2.0815x; 2.0815x over previous
//
#include <hip/hip_runtime.h>
#include <hip/hip_bf16.h>
#include <cstdint>
#include <cstddef>

// Problem constants
#define KBLK 6
#define SL 257
#define BA 64
#define DM 1024
#define NHEAD 16
#define DRED 256
#define HDM 16
#define MR (SL * BA)     // 16448 real rows
#define MP 16512         // 129 * 128 padded rows
#define LNEPS 1e-5f

typedef __hip_bfloat16 bf16;
typedef __attribute__((ext_vector_type(8))) short short8;
typedef __attribute__((ext_vector_type(4))) short short4_t;
typedef __attribute__((ext_vector_type(4))) float f32x4;

// ---------------- async global -> LDS (16B per lane) ----------------
__device__ __forceinline__ void gld_lds16(const void* g, void* l) {
  __builtin_amdgcn_global_load_lds(
      (const __attribute__((address_space(1))) unsigned int*)g,
      (__attribute__((address_space(3))) unsigned int*)l, 16, 0, 0);
}

__device__ __forceinline__ float bf2f(short s) {
  bf16 t = *reinterpret_cast<bf16*>(&s);
  return __bfloat162float(t);
}
__device__ __forceinline__ short f2bf(float f) {
  bf16 t = __float2bfloat16(f);
  return *reinterpret_cast<short*>(&t);
}

// ---------------- fused weight casts (one launch) ----------------
// blocks: [0,2304) wq | [2304,3072) wo | [3072,6144) wfc | [6144,9216) wcp | [9216,9600) wpj(T)
__global__ __launch_bounds__(256) void cast_all_kernel(
    const float* __restrict__ ipw, const float* __restrict__ opw,
    const float* __restrict__ fcw, const float* __restrict__ cpw,
    const float* __restrict__ proj,
    bf16* __restrict__ wq, bf16* __restrict__ wo, bf16* __restrict__ wfc,
    bf16* __restrict__ wcp, bf16* __restrict__ wpj) {
  const int blk = blockIdx.x;
  const int tid = threadIdx.x;
  const float* src;
  bf16* dst;
  int base;
  bool tr = false;
  if (blk < 2304)      { src = ipw; dst = wq;  base = blk * 2048; }
  else if (blk < 3072) { src = opw; dst = wo;  base = (blk - 2304) * 2048; }
  else if (blk < 6144) { src = fcw; dst = wfc; base = (blk - 3072) * 2048; }
  else if (blk < 9216) { src = cpw; dst = wcp; base = (blk - 6144) * 2048; }
  else                 { src = proj; dst = wpj; base = (blk - 9216) * 2048; tr = true; }
  const int idx = base + tid * 8;
  short8 o;
  if (!tr) {
    float4 a = *(const float4*)(src + idx);
    float4 b = *(const float4*)(src + idx + 4);
    o[0] = f2bf(a.x); o[1] = f2bf(a.y); o[2] = f2bf(a.z); o[3] = f2bf(a.w);
    o[4] = f2bf(b.x); o[5] = f2bf(b.y); o[6] = f2bf(b.z); o[7] = f2bf(b.w);
  } else {
    // wpj[n*1024 + k] = proj[k*768 + n]
    int n = idx >> 10, k = idx & 1023;
#pragma unroll
    for (int e = 0; e < 8; ++e) o[e] = f2bf(src[(size_t)(k + e) * 768 + n]);
  }
  *(short8*)(dst + idx) = o;
}

// ---------------- LayerNorm ----------------
// MODE 0: x = bf16(hook); LN(hook) -> hout
// MODE 2: LN(x) -> hout
// MODE 3: LN(x) -> hout at transposed row (b*SL+s)  [ln_post]
template <int MODE>
__global__ __launch_bounds__(256) void ln_kernel(
    const float* __restrict__ hook,
    bf16* __restrict__ x, bf16* __restrict__ hout,
    const float* __restrict__ w, const float* __restrict__ bb) {
  const int row = blockIdx.x;
  const int tid = threadIdx.x;
  const size_t base = (size_t)row * DM + tid * 4;
  float vals[4];
  if (MODE == 0) {
    float4 v = *(const float4*)(hook + base);
    vals[0] = v.x; vals[1] = v.y; vals[2] = v.z; vals[3] = v.w;
    short4_t pk;
#pragma unroll
    for (int j = 0; j < 4; ++j) pk[j] = f2bf(vals[j]);
    *(short4_t*)&x[base] = pk;
  } else {
    short4_t xv = *(const short4_t*)&x[base];
#pragma unroll
    for (int j = 0; j < 4; ++j) vals[j] = bf2f(xv[j]);
  }
  float s1 = vals[0] + vals[1] + vals[2] + vals[3];
  float s2 = vals[0] * vals[0] + vals[1] * vals[1] + vals[2] * vals[2] + vals[3] * vals[3];
#pragma unroll
  for (int o = 32; o >= 1; o >>= 1) {
    s1 += __shfl_down(s1, o);
    s2 += __shfl_down(s2, o);
  }
  __shared__ float red[8];
  if ((tid & 63) == 0) {
    red[tid >> 6] = s1;
    red[4 + (tid >> 6)] = s2;
  }
  __syncthreads();
  s1 = red[0] + red[1] + red[2] + red[3];
  s2 = red[4] + red[5] + red[6] + red[7];
  const float mu = s1 * (1.f / DM);
  const float rs = rsqrtf(s2 * (1.f / DM) - mu * mu + LNEPS);
  size_t orow = row;
  if (MODE == 3) {
    int s = row >> 6, b2 = row & 63;
    orow = (size_t)b2 * SL + s;
  }
  const int c = tid * 4;
  short4_t pk;
#pragma unroll
  for (int j = 0; j < 4; ++j)
    pk[j] = f2bf((vals[j] - mu) * rs * w[c + j] + bb[c + j]);
  *(short4_t*)((char*)hout + (orow * DM + c) * 2) = pk;
}

// ---------------- MFMA attention (unchanged, validated) ----------------
__global__ __launch_bounds__(256) void attn_mfma_kernel(const bf16* __restrict__ qkv,
                                                        bf16* __restrict__ obuf) {
  __shared__ __align__(16) short ql[272][24];
  __shared__ __align__(16) short kl[272][24];
  __shared__ __align__(16) short vt[16][296];
  __shared__ __align__(16) short pl[4][16][40];
  const int bh = blockIdx.x;
  const int b = bh >> 4, h = bh & 15;
  const int tid = threadIdx.x;
  const int wave = tid >> 6, lane = tid & 63;
  const int g = lane >> 4, qi = lane & 15;

  const short8 zero8 = {0, 0, 0, 0, 0, 0, 0, 0};
  const f32x4 fzero = {0.f, 0.f, 0.f, 0.f};

  for (int task = tid; task < 1632; task += 256) {
    int a, rem;
    if (task < 544) { a = 0; rem = task; }
    else if (task < 1088) { a = 1; rem = task - 544; }
    else { a = 2; rem = task - 1088; }
    int row = rem >> 1, half = rem & 1;
    short8 v = zero8;
    if (row < SL)
      v = *(const short8*)((const short*)qkv + (size_t)(row * BA + b) * 768 + a * 256 + h * 16 + half * 8);
    if (a == 0) *(short8*)&ql[row][half * 8] = v;
    else if (a == 1) *(short8*)&kl[row][half * 8] = v;
    else {
#pragma unroll
      for (int j = 0; j < 8; ++j) vt[half * 8 + j][row] = v[j];
    }
  }
  for (int i = tid; i < 16 * 24; i += 256) vt[i / 24][272 + (i % 24)] = 0;
  __syncthreads();

  for (int t = wave; t < 17; t += 4) {
    short8 bq = zero8;
    if (g < 2) bq = *(const short8*)&ql[t * 16 + qi][g * 8];

    f32x4 st[18];
#pragma unroll
    for (int t2 = 0; t2 < 17; ++t2) {
      short8 ak = zero8;
      if (g < 2) ak = *(const short8*)&kl[t2 * 16 + qi][g * 8];
      st[t2] = __builtin_amdgcn_mfma_f32_16x16x32_bf16(ak, bq, fzero, 0, 0, 0);
    }
    float mx = -1e30f;
#pragma unroll
    for (int t2 = 0; t2 < 17; ++t2) {
#pragma unroll
      for (int r = 0; r < 4; ++r) {
        int s = t2 * 16 + g * 4 + r;
        float v = (s <= 256) ? st[t2][r] * 0.25f : -1e30f;
        st[t2][r] = v;
        mx = fmaxf(mx, v);
      }
    }
    mx = fmaxf(mx, __shfl_xor(mx, 16));
    mx = fmaxf(mx, __shfl_xor(mx, 32));
    float ls = 0.f;
#pragma unroll
    for (int t2 = 0; t2 < 17; ++t2) {
#pragma unroll
      for (int r = 0; r < 4; ++r) {
        float p = __expf(st[t2][r] - mx);
        st[t2][r] = p;
        ls += p;
      }
    }
    ls += __shfl_xor(ls, 16);
    ls += __shfl_xor(ls, 32);
    const float inv = 1.f / ls;
#pragma unroll
    for (int t2 = 0; t2 < 17; ++t2)
#pragma unroll
      for (int r = 0; r < 4; ++r) st[t2][r] *= inv;
    st[17] = fzero;

    f32x4 acc = fzero;
#pragma unroll
    for (int tt = 0; tt < 9; ++tt) {
#pragma unroll
      for (int hh = 0; hh < 2; ++hh) {
        int t2 = tt * 2 + hh;
        short4_t pk;
#pragma unroll
        for (int r = 0; r < 4; ++r) pk[r] = f2bf(st[t2][r]);
        *(short4_t*)&pl[wave][qi][hh * 16 + g * 4] = pk;
      }
      short8 pa = *(const short8*)&pl[wave][qi][g * 8];
      short8 bv = *(const short8*)&vt[qi][tt * 32 + g * 8];
      acc = __builtin_amdgcn_mfma_f32_16x16x32_bf16(pa, bv, acc, 0, 0, 0);
    }
#pragma unroll
    for (int r = 0; r < 4; ++r) {
      int qr = t * 16 + g * 4 + r;
      if (qr < SL)
        obuf[(size_t)(qr * BA + b) * DRED + h * 16 + qi] = __float2bfloat16(acc[r]);
    }
  }
}

// ---------------- unified 128x128 GEMM, m97 2-barrier loop, 4 wg/CU ----------------
// C(M,N) = A(M,K) * Bw(N,K)^T + bias.  MFMA operands SWAPPED (mfma(B,A)) so each
// lane's 4 acc elems are column-consecutive -> vectorized float4/short4 epilogue.
// EPI 0: fp32 pure write           EPI 1: bf16 in-place RMW  C += acc + bias
// EPI 2: bf16 quickgelu(acc+bias)  EPI 3: bf16 pure acc+bias
// EPI 4: bf16 in-place  x = wm*hook + (1-wm)*(x + acc + bias)
template <int EPI>
__global__ __launch_bounds__(256, 4) void gemm_kernel(
    const bf16* __restrict__ A, int lda,
    const bf16* __restrict__ Bw, int ldb,
    const float* __restrict__ bias,
    void* __restrict__ C, int ldc,
    int Kdim, int Mreal,
    const float* __restrict__ hook, const float* __restrict__ alphap, int kidx) {
  __shared__ char lds[32768];  // A 16KB | B 16KB, BK=64
  const int tid = threadIdx.x;
  const int wave = tid >> 6, lane = tid & 63;
  const int lrow = lane & 15, lk = lane >> 4;
  const int wr = wave >> 1, wc = wave & 1;

  // XCD-aware bijective swizzle (m204), n-fastest decomposition
  const int gx = gridDim.x, gy = gridDim.y;
  const int nwg = gx * gy;
  const int orig = blockIdx.y * gx + blockIdx.x;
  const int q = nwg >> 3, r = nwg & 7;
  const int xcd = orig & 7, idx = orig >> 3;
  const int wgid = (xcd < r ? xcd * (q + 1) : r * (q + 1) + (xcd - r) * q) + idx;
  const int m0 = (wgid / gy) * 128;
  const int n0 = (wgid % gy) * 128;

  f32x4 acc[4][4];
  const f32x4 zero = {0.f, 0.f, 0.f, 0.f};
#pragma unroll
  for (int i = 0; i < 4; ++i)
#pragma unroll
    for (int j = 0; j < 4; ++j) acc[i][j] = zero;

  const int nk = Kdim >> 6;

  for (int kt = 0; kt < nk; ++kt) {
    const int k0 = kt << 6;
#pragma unroll
    for (int j = 0; j < 4; ++j) {
      int c = wave * 256 + j * 64 + lane;
      int row = c >> 3, segp = c & 7;
      int seg = segp ^ (row & 7);
      const bf16* ga = A + (size_t)(m0 + row) * lda + k0 + seg * 8;
      gld_lds16(ga, &lds[(wave * 256 + j * 64) * 16]);
      const bf16* gb = Bw + (size_t)(n0 + row) * ldb + k0 + seg * 8;
      gld_lds16(gb, &lds[16384 + (wave * 256 + j * 64) * 16]);
    }
    __syncthreads();
    const char* aL = &lds[0];
    const char* bL = aL + 16384;
#pragma unroll
    for (int kh = 0; kh < 2; ++kh) {
      short8 af[4], bfr[4];
#pragma unroll
      for (int i = 0; i < 4; ++i) {
        int rr = wr * 64 + i * 16 + lrow;
        int seg = kh * 4 + lk;
        af[i] = *(const short8*)(aL + rr * 128 + ((seg ^ (rr & 7)) << 4));
      }
#pragma unroll
      for (int j = 0; j < 4; ++j) {
        int rr = wc * 64 + j * 16 + lrow;
        int seg = kh * 4 + lk;
        bfr[j] = *(const short8*)(bL + rr * 128 + ((seg ^ (rr & 7)) << 4));
      }
      // swapped operands: D rows = B-tile cols, D cols (lane&15) = A-tile rows
#pragma unroll
      for (int i = 0; i < 4; ++i)
#pragma unroll
        for (int j = 0; j < 4; ++j)
          acc[i][j] = __builtin_amdgcn_mfma_f32_16x16x32_bf16(bfr[j], af[i], acc[i][j], 0, 0, 0);
    }
    __syncthreads();
  }

  // epilogue: lane holds row = ...+i*16+lrow, cols = ...+j*16+lk*4 .. +3
  float wmg = 0.f, omg = 0.f;
  if (EPI == 4) {
    wmg = 1.f / (1.f + __expf(-alphap[kidx] * 10.f));
    omg = 1.f - wmg;
  }
#pragma unroll
  for (int i = 0; i < 4; ++i) {
    const int row = m0 + wr * 64 + i * 16 + lrow;
    if (row >= Mreal) continue;
#pragma unroll
    for (int j = 0; j < 4; ++j) {
      const int col = n0 + wc * 64 + j * 16 + lk * 4;
      const size_t off = (size_t)row * ldc + col;
      float bv[4] = {0.f, 0.f, 0.f, 0.f};
      if (bias) {
        float4 b4 = *(const float4*)&bias[col];
        bv[0] = b4.x; bv[1] = b4.y; bv[2] = b4.z; bv[3] = b4.w;
      }
      float v[4];
#pragma unroll
      for (int rr = 0; rr < 4; ++rr) v[rr] = acc[i][j][rr] + bv[rr];
      if (EPI == 0) {
        float4 o4 = {v[0], v[1], v[2], v[3]};
        *(float4*)((float*)C + off) = o4;
      } else if (EPI == 2) {
        short4_t pk;
#pragma unroll
        for (int rr = 0; rr < 4; ++rr)
          pk[rr] = f2bf(v[rr] / (1.f + __expf(-1.702f * v[rr])));
        *(short4_t*)((bf16*)C + off) = pk;
      } else if (EPI == 3) {
        short4_t pk;
#pragma unroll
        for (int rr = 0; rr < 4; ++rr) pk[rr] = f2bf(v[rr]);
        *(short4_t*)((bf16*)C + off) = pk;
      } else if (EPI == 1) {
        short4_t xv = *(const short4_t*)((const bf16*)C + off);
        short4_t pk;
#pragma unroll
        for (int rr = 0; rr < 4; ++rr) pk[rr] = f2bf(bf2f(xv[rr]) + v[rr]);
        *(short4_t*)((bf16*)C + off) = pk;
      } else {  // EPI 4
        short4_t xv = *(const short4_t*)((const bf16*)C + off);
        float4 h4 = *(const float4*)&hook[off];
        float hk[4] = {h4.x, h4.y, h4.z, h4.w};
        short4_t pk;
#pragma unroll
        for (int rr = 0; rr < 4; ++rr)
          pk[rr] = f2bf(wmg * hk[rr] + omg * (bf2f(xv[rr]) + v[rr]));
        *(short4_t*)((bf16*)C + off) = pk;
      }
    }
  }
}

// ---------------- driver ----------------
extern "C" void kernel_launch(void* const* d_in, const int* in_sizes, int n_in,
                              void* d_out, int out_size, void* d_ws, size_t ws_size,
                              hipStream_t stream) {
  const float* hook = (const float*)d_in[0];
  const float* alpha = (const float*)d_in[1];
  const float* ipw = (const float*)d_in[2];
  const float* ipb = (const float*)d_in[3];
  const float* opw = (const float*)d_in[4];
  const float* opb = (const float*)d_in[5];
  const float* l1w = (const float*)d_in[6];
  const float* l1b = (const float*)d_in[7];
  const float* l2w = (const float*)d_in[8];
  const float* l2b = (const float*)d_in[9];
  const float* fcw = (const float*)d_in[10];
  const float* fcb = (const float*)d_in[11];
  const float* cpw = (const float*)d_in[12];
  const float* cpb = (const float*)d_in[13];
  const float* lpw = (const float*)d_in[14];
  const float* lpb = (const float*)d_in[15];
  const float* proj = (const float*)d_in[16];

  char* ws = (char*)d_ws;
  size_t off = 0;
  bf16* x = (bf16*)(ws + off); off += (size_t)MP * DM * 2;
  bf16* hbuf = (bf16*)(ws + off); off += (size_t)MP * DM * 2;
  bf16* qkv = (bf16*)(ws + off);
  bf16* mbuf = (bf16*)qkv;  // reuse qkv region for MLP intermediate
  off += (size_t)MP * 1024 * 2;
  bf16* obuf = (bf16*)(ws + off); off += (size_t)MP * DRED * 2;
  bf16* wq = (bf16*)(ws + off); off += (size_t)KBLK * 768 * DM * 2;
  bf16* wo = (bf16*)(ws + off); off += (size_t)KBLK * DM * DRED * 2;
  bf16* wfc = (bf16*)(ws + off); off += (size_t)KBLK * DM * DM * 2;
  bf16* wcp = (bf16*)(ws + off); off += (size_t)KBLK * DM * DM * 2;
  bf16* wpj = (bf16*)(ws + off); off += (size_t)768 * DM * 2;

  // fused weight casts (one launch)
  cast_all_kernel<<<9600, 256, 0, stream>>>(ipw, opw, fcw, cpw, proj,
                                            wq, wo, wfc, wcp, wpj);

  const dim3 gq(MP / 128, 768 / 128);   // N=768 grids (qkv, final proj): 774 wgs
  const dim3 gm(MP / 128, DM / 128);    // N=1024 grids: 1032 wgs

  for (int i = 0; i < KBLK; ++i) {
    if (i == 0)
      ln_kernel<0><<<MR, 256, 0, stream>>>(hook, x, hbuf, l1w, l1b);
    else
      ln_kernel<2><<<MR, 256, 0, stream>>>(nullptr, x, hbuf, l1w + i * DM, l1b + i * DM);
    // qkv = LN1(x) @ ipw^T + ipb (bf16)
    gemm_kernel<3><<<gq, 256, 0, stream>>>(hbuf, DM, wq + (size_t)i * 768 * DM, DM,
                                           ipb + i * 768, qkv, 768, DM, MR,
                                           nullptr, nullptr, 0);
    attn_mfma_kernel<<<BA * NHEAD, 256, 0, stream>>>(qkv, obuf);
    // x += attn_out @ opw^T + opb   (in-place RMW, disjoint tiles)
    gemm_kernel<1><<<gm, 256, 0, stream>>>(obuf, DRED, wo + (size_t)i * DM * DRED, DRED,
                                           opb + i * DM, x, DM, DRED, MR,
                                           nullptr, nullptr, 0);
    ln_kernel<2><<<MR, 256, 0, stream>>>(nullptr, x, hbuf, l2w + i * DM, l2b + i * DM);
    // mbuf = quickgelu(LN2(x) @ fcw^T + fcb)
    gemm_kernel<2><<<gm, 256, 0, stream>>>(hbuf, DM, wfc + (size_t)i * DM * DM, DM,
                                           fcb + i * DM, mbuf, DM, DM, MR,
                                           nullptr, nullptr, 0);
    // x = [gate with next block's hook] (x + mbuf @ cpw^T + cpb)  (in-place RMW)
    if (i + 1 < KBLK)
      gemm_kernel<4><<<gm, 256, 0, stream>>>(mbuf, DM, wcp + (size_t)i * DM * DM, DM,
                                             cpb + i * DM, x, DM, DM, MR,
                                             hook + (size_t)(i + 1) * MR * DM, alpha, i + 1);
    else
      gemm_kernel<1><<<gm, 256, 0, stream>>>(mbuf, DM, wcp + (size_t)i * DM * DM, DM,
                                             cpb + i * DM, x, DM, DM, MR,
                                             nullptr, nullptr, 0);
  }
  // final: LN_post (transposed to (B,S,D)) then @ proj -> d_out (fp32)
  ln_kernel<3><<<MR, 256, 0, stream>>>(nullptr, x, hbuf, lpw, lpb);
  gemm_kernel<0><<<gq, 256, 0, stream>>>(hbuf, DM, wpj, DM, nullptr,
                                         (float*)d_out, 768, DM, MR,
                                         nullptr, nullptr, 0);
}